// Round 6
// baseline (208.973 us; speedup 1.0000x reference)
//
#include <hip/hip_runtime.h>

// Problem: S=8192, K=1024, O=4096
// out_q[s,o] = clip(round(int8dot(x[s,:], w[o,:]) * sx*sw/sy[s]), -128, 127)
// d_out = [ out_q as float (S*O) | scale_y (S) ]
//
// R11: faithful m201-template port (R9 post-mortem: its 8-MFMA windows and
// 9 barriers/32-MFMA were the regression, not 1 blk/CU).
// BM=BN=256, 512 thr = 8 waves (2Mx4N), wave tile 128x64.
// 4-slot LDS ring (4 x 32KB = 128 KB), prefetch depth 3 slots.
// 2 phases per K=64 slot, each: {ds_read | 2 stage loads | BAR | setprio(1)
// 16 MFMA setprio(0) | [slot end: vmcnt(8)] | BAR}. vmcnt(8) = 2 newer slots
// (4 loads each) stay in flight; never 0 until the tail. Pack layout
// byte-identical to the verified R5/R8 image.

#define S_DIM 8192
#define K_DIM 1024
#define O_DIM 4096
#define BM 256
#define BN 256
#define BK 64
#define NITER (K_DIM / BK)           // 16 K-slots
#define TILE_BYTES (128 * BK)        // 8 KB band-ktile (pack layout unit)
#define BAND_BYTES (NITER * TILE_BYTES)  // 128 KB per 128-row band
#define A_SLOT (2 * TILE_BYTES)      // 16 KB: rows 0-127, 128-255
#define B_SLOT (2 * TILE_BYTES)      // 16 KB: cols 0-127, 128-255

using i32x4 = __attribute__((ext_vector_type(4))) int;

__device__ __forceinline__ void load_lds16(const void* g, void* l) {
  __builtin_amdgcn_global_load_lds(
      (const __attribute__((address_space(1))) void*)g,
      (__attribute__((address_space(3))) void*)l, 16, 0, 0);
}

#define FENCE() asm volatile("" ::: "memory")

// ---------------- pack: int32 -> int8 into STAGING-TILE layout ----------------
// (byte-identical to the verified R5/R8 pack)
// Layout: tile t = band*16 + ktile (band = row/128, ktile = k/64), 8 KB each.
// Within tile: byte r*64 + cs*16 holds chunk (cs ^ (r&3)) of row band*128+r.
__global__ void pack_kernel(const int* __restrict__ xi, const int* __restrict__ wi,
                            const float* __restrict__ sy,
                            uint4* __restrict__ ap, uint4* __restrict__ bp,
                            float* __restrict__ out_sy) {
  const int tid = blockIdx.x * blockDim.x + threadIdx.x;
  const int nA = S_DIM * K_DIM / 16;  // 512K chunks
  const int nB = O_DIM * K_DIM / 16;  // 256K chunks

  const int* src;
  uint4* dst;
  int j;
  if (tid < nA) {
    src = xi; dst = ap; j = tid;
  } else if (tid < nA + nB) {
    src = wi; dst = bp; j = tid - nA;
  } else {
    return;
  }
  const int t = j >> 9;          // tile index (512 chunks/tile)
  const int idx = j & 511;
  const int r = idx >> 2;        // row within tile 0..127
  const int cs = idx & 3;        // chunk slot
  const int c = cs ^ (r & 3);    // global chunk (swizzle)
  const int band = t >> 4;       // 16 ktiles per band
  const int kt = t & 15;
  const int row = band * 128 + r;
  const int4* s4 = (const int4*)src + row * 256 + kt * 16 + c * 4;
  int4 v0 = s4[0], v1 = s4[1], v2 = s4[2], v3 = s4[3];
  uint4 o;
  o.x = (v0.x & 0xff) | ((v0.y & 0xff) << 8) | ((v0.z & 0xff) << 16) | (((unsigned)v0.w & 0xff) << 24);
  o.y = (v1.x & 0xff) | ((v1.y & 0xff) << 8) | ((v1.z & 0xff) << 16) | (((unsigned)v1.w & 0xff) << 24);
  o.z = (v2.x & 0xff) | ((v2.y & 0xff) << 8) | ((v2.z & 0xff) << 16) | (((unsigned)v2.w & 0xff) << 24);
  o.w = (v3.x & 0xff) | ((v3.y & 0xff) << 8) | ((v3.z & 0xff) << 16) | (((unsigned)v3.w & 0xff) << 24);
  dst[j] = o;
  if (tid < S_DIM) out_sy[tid] = sy[tid];
}

// ---------------- int8 MFMA GEMM, 256x256, 2x16-MFMA phases, ring-4 ----------
// Wave (wm 0..1, wn 0..3) owns rows wm*128..+127, cols wn*64..+63:
// 8 M-frags x 4 N-frags of 16x16x64 = 32 MFMA per K-slot, 2 phases x 16.
// Wait pattern (end of slot it, before final barrier):
//   outstanding = slots it+1 (oldest 4) .. it+3 (newest 4, issued this slot);
//   vmcnt(8) drains slot it+1 -> ready for next iter. Tail: 4 -> 0.
// Slot lifetime: stage(it+3) overwrites slot (it-1)%4; issued after slot it's
// entry barrier, which every wave crossed only after its slot-(it-1) MFMAs
// (and thus their feeding ds_reads) completed.
__global__ __launch_bounds__(512, 2) void gemm_i8_kernel(
    const signed char* __restrict__ Ap,  // tiled-packed x
    const signed char* __restrict__ Bp,  // tiled-packed w
    const float* __restrict__ sx, const float* __restrict__ sw,
    const float* __restrict__ sy, float* __restrict__ out) {
  __shared__ __align__(16) signed char As[4][A_SLOT];  // 64 KB
  __shared__ __align__(16) signed char Bs[4][B_SLOT];  // 64 KB

  const int tid = threadIdx.x;
  const int wave = tid >> 6;
  const int lane = tid & 63;
  const int wm = wave >> 2;  // 0..1: wave row (128 rows each)
  const int wn = wave & 3;   // 0..3: wave col (64 cols each)
  const int rowBase = blockIdx.x * BM;
  const int colBase = blockIdx.y * BN;

  const int soff = wave * 1024 + lane * 16;  // 512 thr x 16 B = 8 KB per call
  const signed char* gA0 = Ap + (size_t)(2 * blockIdx.x) * BAND_BYTES + soff;
  const signed char* gA1 = Ap + (size_t)(2 * blockIdx.x + 1) * BAND_BYTES + soff;
  const signed char* gB0 = Bp + (size_t)(2 * blockIdx.y) * BAND_BYTES + soff;
  const signed char* gB1 = Bp + (size_t)(2 * blockIdx.y + 1) * BAND_BYTES + soff;
  signed char* ldsA = (signed char*)As + soff;  // + slot*A_SLOT (+TILE half1)
  signed char* ldsB = (signed char*)Bs + soff;

  i32x4 acc[8][4] = {};

  const int fr = lane & 15;                            // fragment row/col
  const int fq = (((lane >> 4) ^ (fr & 3)) & 3) * 16;  // swizzled chunk slot

  // Per-wave read bases (swizzle uses (row&3) == (fr&3), invariant here).
  // A row = wm*128 + mi*16 + fr -> byte wm*8192 + mi*1024 + fr*64 + fq.
  // B col = wn*64 + ni*16 + fr  -> byte (wn>>1)*8192 + ((wn&1)*64+ni*16+fr)*64 + fq.
  const int aoff = wm * TILE_BYTES + fr * 64 + fq;                          // + mi*1024
  const int boff = (wn >> 1) * TILE_BYTES + ((wn & 1) * 64 + fr) * 64 + fq; // + ni*1024

  // Prologue: stage slots 0,1,2 as three ORDERED groups of 4 loads.
  load_lds16(gA0, ldsA);
  load_lds16(gA1, ldsA + TILE_BYTES);
  load_lds16(gB0, ldsB);
  load_lds16(gB1, ldsB + TILE_BYTES);
  FENCE();
  load_lds16(gA0 + TILE_BYTES, ldsA + A_SLOT);
  load_lds16(gA1 + TILE_BYTES, ldsA + A_SLOT + TILE_BYTES);
  load_lds16(gB0 + TILE_BYTES, ldsB + B_SLOT);
  load_lds16(gB1 + TILE_BYTES, ldsB + B_SLOT + TILE_BYTES);
  FENCE();
  load_lds16(gA0 + 2 * TILE_BYTES, ldsA + 2 * A_SLOT);
  load_lds16(gA1 + 2 * TILE_BYTES, ldsA + 2 * A_SLOT + TILE_BYTES);
  load_lds16(gB0 + 2 * TILE_BYTES, ldsB + 2 * B_SLOT);
  load_lds16(gB1 + 2 * TILE_BYTES, ldsB + 2 * B_SLOT + TILE_BYTES);
  FENCE();
  asm volatile("s_waitcnt vmcnt(8)" ::: "memory");  // slot 0 landed
  __builtin_amdgcn_s_barrier();                     // slot 0 published

#pragma unroll
  for (int it = 0; it < NITER; ++it) {
    const signed char* curA = As[it & 3] + aoff;
    const signed char* curB = Bs[it & 3] + boff;
    const int pslot = (it + 3) & 3;
    const size_t pgoff = (size_t)(it + 3) * TILE_BYTES;
    const bool pf = (it + 3) < NITER;

    // ---------------- phase 0: acc[0..3][*] ----------------
    i32x4 bf[4];
#pragma unroll
    for (int ni = 0; ni < 4; ++ni)
      bf[ni] = *(const i32x4*)(curB + ni * 1024);
    i32x4 af[4];
#pragma unroll
    for (int mi = 0; mi < 4; ++mi)
      af[mi] = *(const i32x4*)(curA + mi * 1024);
    if (pf) {  // stage A of slot it+3
      load_lds16(gA0 + pgoff, ldsA + pslot * A_SLOT);
      load_lds16(gA1 + pgoff, ldsA + pslot * A_SLOT + TILE_BYTES);
    }
    __builtin_amdgcn_s_barrier();  // end read window
    __builtin_amdgcn_s_setprio(1);
#pragma unroll
    for (int mi = 0; mi < 4; ++mi)
#pragma unroll
      for (int ni = 0; ni < 4; ++ni)
        acc[mi][ni] =
            __builtin_amdgcn_mfma_i32_16x16x64_i8(af[mi], bf[ni], acc[mi][ni], 0, 0, 0);
    __builtin_amdgcn_s_setprio(0);
    __builtin_amdgcn_s_barrier();  // end MFMA window

    // ---------------- phase 1: acc[4..7][*] ----------------
#pragma unroll
    for (int mi = 0; mi < 4; ++mi)
      af[mi] = *(const i32x4*)(curA + (mi + 4) * 1024);
    if (pf) {  // stage B of slot it+3
      load_lds16(gB0 + pgoff, ldsB + pslot * B_SLOT);
      load_lds16(gB1 + pgoff, ldsB + pslot * B_SLOT + TILE_BYTES);
    }
    __builtin_amdgcn_s_barrier();  // end read window
    __builtin_amdgcn_s_setprio(1);
#pragma unroll
    for (int mi = 0; mi < 4; ++mi)
#pragma unroll
      for (int ni = 0; ni < 4; ++ni)
        acc[mi + 4][ni] =
            __builtin_amdgcn_mfma_i32_16x16x64_i8(af[mi], bf[ni], acc[mi + 4][ni], 0, 0, 0);
    __builtin_amdgcn_s_setprio(0);

    // End of slot: confirm slot it+1; keep newer slots in flight.
    if (it + 3 < NITER) {
      asm volatile("s_waitcnt vmcnt(8)" ::: "memory");
    } else if (it + 2 < NITER) {
      asm volatile("s_waitcnt vmcnt(4)" ::: "memory");
    } else if (it + 1 < NITER) {
      asm volatile("s_waitcnt vmcnt(0)" ::: "memory");
    }
    __builtin_amdgcn_s_barrier();  // end slot; next slot published
  }

  // Epilogue. C/D layout per 16x16: col = lane&15, row = (lane>>4)*4 + reg.
  const float sxw = sx[0] * sw[0];
  const int quad = lane >> 4;
#pragma unroll
  for (int mi = 0; mi < 8; ++mi) {
#pragma unroll
    for (int r = 0; r < 4; ++r) {
      const int s = rowBase + wm * 128 + mi * 16 + quad * 4 + r;
      const float rs = sxw / sy[s];
      float* orow = out + (size_t)s * O_DIM + colBase + wn * 64 + fr;
#pragma unroll
      for (int ni = 0; ni < 4; ++ni) {
        float f = rintf((float)acc[mi][ni][r] * rs);
        f = fminf(127.0f, fmaxf(-128.0f, f));
        orow[ni * 16] = f;
      }
    }
  }
}

extern "C" void kernel_launch(void* const* d_in, const int* in_sizes, int n_in,
                              void* d_out, int out_size, void* d_ws, size_t ws_size,
                              hipStream_t stream) {
  const int* x = (const int*)d_in[0];        // [S,K] int8 values as int32
  const int* w = (const int*)d_in[1];        // [O,K] int8 values as int32
  const float* sx = (const float*)d_in[2];
  const float* sw = (const float*)d_in[3];
  const float* sy = (const float*)d_in[4];   // [S]
  float* out = (float*)d_out;

  uint4* ap = (uint4*)d_ws;                                   // 8 MB tiled A
  uint4* bp = ap + (size_t)S_DIM * K_DIM / 16;                // 4 MB tiled B

  const int total = S_DIM * K_DIM / 16 + O_DIM * K_DIM / 16;  // 768K threads
  pack_kernel<<<(total + 255) / 256, 256, 0, stream>>>(
      x, w, sy, ap, bp, out + (size_t)S_DIM * O_DIM);

  dim3 grid(S_DIM / BM, O_DIM / BN);  // (32, 16)
  gemm_i8_kernel<<<grid, 512, 0, stream>>>(
      (const signed char*)ap, (const signed char*)bp, sx, sw, sy, out);
}

// Round 7
// 205.951 us; speedup vs baseline: 1.0147x; 1.0147x over previous
//
#include <hip/hip_runtime.h>

// Problem: S=8192, K=1024, O=4096
// out_q[s,o] = clip(round(int8dot(x[s,:], w[o,:]) * sx*sw/sy[s]), -128, 127)
// d_out = [ out_q as float (S*O) | scale_y (S) ]
//
// R12 = R8 chassis (best, 199.6 us: 256x128 tile, ring-3, vmcnt(3),
// 16 waves/CU) with the MFMA switched 16x16x64_i8 -> 32x32x32_i8:
// +12% matrix-pipe rate (4404 vs 3944 TOPS), half the MFMA instructions
// (8 vs 16 per wave per K-tile), same fragment bytes, same packed image.
// History: R7 ring3@128^2 -20us (occupancy); R8 0 (counted-vmcnt null on
// 2-phase); R9 4-phase -12.7; R10 XCD swizzle 0; R11 faithful 8-phase -9.4.
// Schedule axis exhausted; this attacks instruction efficiency.
//
// 32x32x32 fragment mapping (extension of the verified 16x16x64 one):
//   A: row = lane&31, k-bytes [kb + (lane>>5)*16, +16), kb in {0,32}
//      -> chunk c = 2*kbi + h, stored at slot c ^ (row&3) in the pack image.
//   B: col = lane&31, same k split.
//   C/D: col = lane&31, row = (reg&3) + 8*(reg>>2) + 4*(lane>>5)  [m74/m101]
// Bank histogram of the new read == the verified zero-conflict 16x16 one
// (8 slot-classes x 8 lanes per wave read).

#define S_DIM 8192
#define K_DIM 1024
#define O_DIM 4096
#define BM 256
#define BN 128
#define BK 64
#define NITER (K_DIM / BK)
#define TILE_BYTES (128 * BK)   // 8192 B band-tile (pack layout unit)
#define A_SLOT (2 * TILE_BYTES) // 16 KB: two band-tiles stacked
#define B_SLOT TILE_BYTES       // 8 KB

using i32x4 = __attribute__((ext_vector_type(4))) int;
using i32x16 = __attribute__((ext_vector_type(16))) int;

__device__ __forceinline__ void load_lds16(const void* g, void* l) {
  __builtin_amdgcn_global_load_lds(
      (const __attribute__((address_space(1))) void*)g,
      (__attribute__((address_space(3))) void*)l, 16, 0, 0);
}

// ---------------- pack: int32 -> int8 into STAGING-TILE layout ----------------
// (byte-identical to the verified R5/R8 pack)
// Layout: tile t = band*16 + ktile (band = row/128, ktile = k/64), 8 KB each.
// Within tile: byte r*64 + cs*16 holds chunk (cs ^ (r&3)) of row band*128+r.
__global__ void pack_kernel(const int* __restrict__ xi, const int* __restrict__ wi,
                            const float* __restrict__ sy,
                            uint4* __restrict__ ap, uint4* __restrict__ bp,
                            float* __restrict__ out_sy) {
  const int tid = blockIdx.x * blockDim.x + threadIdx.x;
  const int nA = S_DIM * K_DIM / 16;  // 512K chunks
  const int nB = O_DIM * K_DIM / 16;  // 256K chunks

  const int* src;
  uint4* dst;
  int j;
  if (tid < nA) {
    src = xi; dst = ap; j = tid;
  } else if (tid < nA + nB) {
    src = wi; dst = bp; j = tid - nA;
  } else {
    return;
  }
  const int t = j >> 9;          // tile index (512 chunks/tile)
  const int idx = j & 511;
  const int r = idx >> 2;        // row within tile 0..127
  const int cs = idx & 3;        // chunk slot
  const int c = cs ^ (r & 3);    // global chunk (swizzle)
  const int band = t >> 4;       // 16 ktiles per band
  const int kt = t & 15;
  const int row = band * 128 + r;
  const int4* s4 = (const int4*)src + row * 256 + kt * 16 + c * 4;
  int4 v0 = s4[0], v1 = s4[1], v2 = s4[2], v3 = s4[3];
  uint4 o;
  o.x = (v0.x & 0xff) | ((v0.y & 0xff) << 8) | ((v0.z & 0xff) << 16) | (((unsigned)v0.w & 0xff) << 24);
  o.y = (v1.x & 0xff) | ((v1.y & 0xff) << 8) | ((v1.z & 0xff) << 16) | (((unsigned)v1.w & 0xff) << 24);
  o.z = (v2.x & 0xff) | ((v2.y & 0xff) << 8) | ((v2.z & 0xff) << 16) | (((unsigned)v2.w & 0xff) << 24);
  o.w = (v3.x & 0xff) | ((v3.y & 0xff) << 8) | ((v3.z & 0xff) << 16) | (((unsigned)v3.w & 0xff) << 24);
  dst[j] = o;
  if (tid < S_DIM) out_sy[tid] = sy[tid];
}

// ---------------- int8 MFMA GEMM, 256x128 tile, ring-3, 32x32x32 ------------
// 512 threads = 8 waves in 4x2; wave owns 64x64 = 2x2 grid of 32x32x32 tiles.
// 3-slot LDS ring (72 KB, 2 blk/CU = 16 waves/CU), 2-deep prefetch:
//   s_waitcnt vmcnt(3) lgkmcnt(0) ; s_barrier ; issue stage(t+2) ; compute(t)
__global__ __launch_bounds__(512, 4) void gemm_i8_kernel(
    const signed char* __restrict__ Ap,  // tiled-packed x
    const signed char* __restrict__ Bp,  // tiled-packed w
    const float* __restrict__ sx, const float* __restrict__ sw,
    const float* __restrict__ sy, float* __restrict__ out) {
  __shared__ __align__(16) signed char As[3][A_SLOT];  // 48 KB
  __shared__ __align__(16) signed char Bs[3][B_SLOT];  // 24 KB

  const int tid = threadIdx.x;
  const int wave = tid >> 6;
  const int lane = tid & 63;
  const int wm = wave >> 1;  // 0..3: wave row in block (64 rows each)
  const int wn = wave & 1;   // 0..1: wave col in block (64 cols each)
  const int rowBase = blockIdx.x * BM;
  const int colBase = blockIdx.y * BN;

  const int soff = wave * 1024 + lane * 16;  // 8 waves cover 8 KB per call
  const signed char* gA0 = Ap + (size_t)(2 * blockIdx.x) * NITER * TILE_BYTES + soff;
  const signed char* gA1 = Ap + (size_t)(2 * blockIdx.x + 1) * NITER * TILE_BYTES + soff;
  const signed char* gB  = Bp + (size_t)blockIdx.y * NITER * TILE_BYTES + soff;
  signed char* ldsA = (signed char*)As + soff;  // + slot*A_SLOT (+TILE for half1)
  signed char* ldsB = (signed char*)Bs + soff;  // + slot*B_SLOT

  i32x16 acc[2][2] = {};

  const int r32 = lane & 31;   // fragment row (A) / col (B)
  const int h = lane >> 5;     // k-half selector
  // Stored slot of chunk c for row r: c ^ (r&3). Needed chunk: 2*kbi + h.
  const int sl0 = ((h) ^ (r32 & 3)) * 16;      // kbi = 0 (k 0..31)
  const int sl1 = ((2 + h) ^ (r32 & 3)) * 16;  // kbi = 1 (k 32..63)
  // A row = wm*64 + mi*32 + r32 -> band wm>>1, in-band (wm&1)*64 + mi*32 + r32
  const int arow = (wm >> 1) * TILE_BYTES + ((wm & 1) * 64 + r32) * 64;  // + mi*2048
  // B col = wn*64 + ni*32 + r32 (single 128-col band)
  const int brow = (wn * 64 + r32) * 64;                                 // + ni*2048

  // Prologue: stage K-tiles 0 and 1 into ring slots 0 and 1 (ordered groups).
  load_lds16(gA0, ldsA);
  load_lds16(gA1, ldsA + TILE_BYTES);
  load_lds16(gB, ldsB);
  asm volatile("" ::: "memory");
  {
    const size_t goff = TILE_BYTES;
    load_lds16(gA0 + goff, ldsA + A_SLOT);
    load_lds16(gA1 + goff, ldsA + A_SLOT + TILE_BYTES);
    load_lds16(gB + goff, ldsB + B_SLOT);
  }

#pragma unroll
  for (int it = 0; it < NITER; ++it) {
    // Drain own stage(it) (oldest 3); keep stage(it+1)'s 3 in flight.
    if (it + 1 < NITER) {
      asm volatile("s_waitcnt vmcnt(3) lgkmcnt(0)" ::: "memory");
    } else {
      asm volatile("s_waitcnt vmcnt(0) lgkmcnt(0)" ::: "memory");
    }
    __builtin_amdgcn_s_barrier();
    asm volatile("" ::: "memory");  // no memory op crosses the barrier

    if (it + 2 < NITER) {  // 2-deep prefetch into ring slot (it+2)%3
      const int slot = (it + 2) % 3;
      const size_t goff = (size_t)(it + 2) * TILE_BYTES;
      load_lds16(gA0 + goff, ldsA + slot * A_SLOT);
      load_lds16(gA1 + goff, ldsA + slot * A_SLOT + TILE_BYTES);
      load_lds16(gB + goff, ldsB + slot * B_SLOT);
    }

    const signed char* curA = As[it % 3];
    const signed char* curB = Bs[it % 3];

#pragma unroll
    for (int kbi = 0; kbi < 2; ++kbi) {
      const int ss = kbi ? sl1 : sl0;
      i32x4 a0 = *(const i32x4*)(curA + arow + ss);
      i32x4 a1 = *(const i32x4*)(curA + arow + 2048 + ss);
      i32x4 b0 = *(const i32x4*)(curB + brow + ss);
      i32x4 b1 = *(const i32x4*)(curB + brow + 2048 + ss);
      acc[0][0] = __builtin_amdgcn_mfma_i32_32x32x32_i8(a0, b0, acc[0][0], 0, 0, 0);
      acc[0][1] = __builtin_amdgcn_mfma_i32_32x32x32_i8(a0, b1, acc[0][1], 0, 0, 0);
      acc[1][0] = __builtin_amdgcn_mfma_i32_32x32x32_i8(a1, b0, acc[1][0], 0, 0, 0);
      acc[1][1] = __builtin_amdgcn_mfma_i32_32x32x32_i8(a1, b1, acc[1][1], 0, 0, 0);
    }
  }

  // Epilogue. 32x32 C/D: col = lane&31, row = (reg&3) + 8*(reg>>2) + 4*h.
  const float sxw = sx[0] * sw[0];
#pragma unroll
  for (int mi = 0; mi < 2; ++mi) {
#pragma unroll
    for (int reg = 0; reg < 16; ++reg) {
      const int row = (reg & 3) + 8 * (reg >> 2) + 4 * h;
      const int s = rowBase + wm * 64 + mi * 32 + row;
      const float rs = sxw / sy[s];
      float* orow = out + (size_t)s * O_DIM + colBase + wn * 64 + r32;
#pragma unroll
      for (int ni = 0; ni < 2; ++ni) {
        float f = rintf((float)acc[mi][ni][reg] * rs);
        f = fminf(127.0f, fmaxf(-128.0f, f));
        orow[ni * 32] = f;
      }
    }
  }
}

extern "C" void kernel_launch(void* const* d_in, const int* in_sizes, int n_in,
                              void* d_out, int out_size, void* d_ws, size_t ws_size,
                              hipStream_t stream) {
  const int* x = (const int*)d_in[0];        // [S,K] int8 values as int32
  const int* w = (const int*)d_in[1];        // [O,K] int8 values as int32
  const float* sx = (const float*)d_in[2];
  const float* sw = (const float*)d_in[3];
  const float* sy = (const float*)d_in[4];   // [S]
  float* out = (float*)d_out;

  uint4* ap = (uint4*)d_ws;                                   // 8 MB tiled A
  uint4* bp = ap + (size_t)S_DIM * K_DIM / 16;                // 4 MB tiled B

  const int total = S_DIM * K_DIM / 16 + O_DIM * K_DIM / 16;  // 768K threads
  pack_kernel<<<(total + 255) / 256, 256, 0, stream>>>(
      x, w, sy, ap, bp, out + (size_t)S_DIM * O_DIM);

  dim3 grid(S_DIM / BM, O_DIM / BN);  // (32, 32)
  gemm_i8_kernel<<<grid, 512, 0, stream>>>(
      (const signed char*)ap, (const signed char*)bp, sx, sw, sy, out);
}